// Round 17
// baseline (108.362 us; speedup 1.0000x reference)
//
#include <hip/hip_runtime.h>
#include <hip/hip_bf16.h>
#include <stdint.h>

namespace {

constexpr float EPSF = 1e-5f;
constexpr float L2E = 1.4426950408889634f;
constexpr float QK_SCALE = 0.17677669529663687f;  // 32^-0.5
constexpr float SCALE2 = QK_SCALE * L2E;          // folded for exp2

typedef __attribute__((ext_vector_type(8))) short short8;
typedef __attribute__((ext_vector_type(4))) float f32x4;

#if __has_builtin(__builtin_amdgcn_exp2f)
__device__ __forceinline__ float fexp2(float x) { return __builtin_amdgcn_exp2f(x); }
#else
__device__ __forceinline__ float fexp2(float x) { return __expf(x * 0.6931471805599453f); }
#endif

__device__ __forceinline__ uint32_t pk2(float a, float b) {  // RNE pair -> v_cvt_pk_bf16_f32
  union { __hip_bfloat162 h; uint32_t u; } cv;
  cv.h.x = __float2bfloat16(a);
  cv.h.y = __float2bfloat16(b);
  return cv.u;
}
__device__ __forceinline__ uint16_t bf1(float f) {
  union { __hip_bfloat16 h; uint16_t u; } cv;
  cv.h = __float2bfloat16(f);
  return cv.u;
}
__device__ __forceinline__ float clip1(float v) { return fminf(fmaxf(v, -1.f), 1.f); }

// async global->LDS copy, 16B per lane; lds base must be wave-uniform.
__device__ __forceinline__ void async_cp16(const uint16_t* g, uint16_t* l) {
  __builtin_amdgcn_global_load_lds(
      (const __attribute__((address_space(1))) uint32_t*)g,
      (__attribute__((address_space(3))) uint32_t*)l, 16, 0, 0);
}

// ---------------- K0: fold BN scales into bf16 weights, fragment-tile layouts ----------------
// wqkvb[512][128] row-major (k1).
// For k345 (LDS-staged), tile layout [tile][c:16][g:4][jj:8]:
//   wpb2[dt*8+kk][c][g][jj] = Wpfold[dt*16+c][kk*32 + g*8 + jj]            (dt<8, kk<8)
//   w1p2[d1t*4+kk][c][g][jj] = W1fold[d1t*16+c][kk*32 + sigma(g,jj)]      (d1t<16, kk<4)
//   w2p2[d2t*8+kk2][c][g][jj] = W2fold[d2t*16+c][kk2*32 + sigma(g,jj)]    (d2t<8, kk2<8)
// sigma(g,j) = j<4 ? 4g+j : 16+4g+(j-4)
__global__ void k0_fold(
    const float* __restrict__ Wq, const float* __restrict__ gq, const float* __restrict__ bq,
    const float* __restrict__ mq, const float* __restrict__ vq,
    const float* __restrict__ Wp, const float* __restrict__ gp, const float* __restrict__ bp,
    const float* __restrict__ mp, const float* __restrict__ vp,
    const float* __restrict__ W1, const float* __restrict__ g1, const float* __restrict__ b1,
    const float* __restrict__ m1, const float* __restrict__ v1,
    const float* __restrict__ W2, const float* __restrict__ g2, const float* __restrict__ b2,
    const float* __restrict__ m2, const float* __restrict__ v2,
    uint16_t* __restrict__ wqkvb, float* __restrict__ shq,
    uint16_t* __restrict__ wpb, float* __restrict__ shp,
    uint16_t* __restrict__ w1p, float* __restrict__ sh1,
    uint16_t* __restrict__ w2p, float* __restrict__ sh2) {
  int id = blockIdx.x * 256 + threadIdx.x;
  if (id < 65536) {
    int d = id >> 7;
    wqkvb[id] = bf1(Wq[id] * (gq[d] * rsqrtf(vq[d] + EPSF)));
  } else if (id < 98304) {
    int j = id - 65536;
    int jj = j & 7, g = (j >> 3) & 3, cc = (j >> 5) & 15, kk = (j >> 9) & 7, dt = (j >> 12) & 7;
    int row = dt * 16 + cc;
    int col = kk * 32 + g * 8 + jj;
    wpb[j] = bf1(Wp[row * 256 + col] * (gp[row] * rsqrtf(vp[row] + EPSF)));
  } else if (id < 131072) {
    int j = id - 98304;
    int jj = j & 7, g = (j >> 3) & 3, cc = (j >> 5) & 15, kk = (j >> 9) & 3, d1t = (j >> 11) & 15;
    int row = d1t * 16 + cc;
    int col = kk * 32 + (jj < 4 ? 4 * g + jj : 16 + 4 * g + (jj - 4));
    w1p[j] = bf1(W1[row * 128 + col] * (g1[row] * rsqrtf(v1[row] + EPSF)));
  } else if (id < 163840) {
    int j = id - 131072;
    int jj = j & 7, g = (j >> 3) & 3, cc = (j >> 5) & 15, kk2 = (j >> 9) & 7, d2t = (j >> 12) & 7;
    int row = d2t * 16 + cc;
    int col = kk2 * 32 + (jj < 4 ? 4 * g + jj : 16 + 4 * g + (jj - 4));
    w2p[j] = bf1(W2[row * 256 + col] * (g2[row] * rsqrtf(v2[row] + EPSF)));
  } else if (id < 164864) {
    int j = id - 163840;
    if (j < 512)      shq[j] = bq[j] - mq[j] * (gq[j] * rsqrtf(vq[j] + EPSF));
    else if (j < 640) { int d = j - 512; shp[d] = bp[d] - mp[d] * (gp[d] * rsqrtf(vp[d] + EPSF)); }
    else if (j < 896) { int d = j - 640; sh1[d] = b1[d] - m1[d] * (g1[d] * rsqrtf(v1[d] + EPSF)); }
    else              { int d = j - 896; sh2[d] = b2[d] - m2[d] * (g2[d] * rsqrtf(v2[d] + EPSF)); }
  }
}

// ---------------- K1: MFMA qkv = BN(x_in @ Wqkv^T) -> qt / kws / vt2, bf16 (R11 version) ----
__global__ __launch_bounds__(256) void k1_qkv(
    const float* __restrict__ x, const uint16_t* __restrict__ wqkvb, const float* __restrict__ shq,
    uint16_t* __restrict__ qt, uint16_t* __restrict__ kws, uint16_t* __restrict__ vt) {
  __shared__ float xs[128][36];
  __shared__ uint16_t ys[4][2][16][136];
  const int t = threadIdx.x;
  const int blk = ((blockIdx.x & 7) << 7) | (blockIdx.x >> 3);  // 1024 bijective XCD chunks
  const int b = blk >> 5, n0 = (blk & 31) << 5;
  {
    const int row = t >> 1, col = (t & 1) << 4;
    const float* xp = x + (size_t)b * (128 * 1024) + (size_t)row * 1024 + n0 + col;
    *(float4*)&xs[row][col]      = *(const float4*)xp;
    *(float4*)&xs[row][col + 4]  = *(const float4*)(xp + 4);
    *(float4*)&xs[row][col + 8]  = *(const float4*)(xp + 8);
    *(float4*)&xs[row][col + 12] = *(const float4*)(xp + 12);
  }
  __syncthreads();
  const int w = t >> 6, l = t & 63, c = l & 15, g = l >> 4;
  union U { uint4 u; short8 s; };
  U bf[2][4];
  #pragma unroll
  for (int tt = 0; tt < 2; ++tt) {
    const int tok = tt * 16 + c;
    #pragma unroll
    for (int kk = 0; kk < 4; ++kk) {
      const int k0i = kk * 32 + g * 8;
      bf[tt][kk].u = make_uint4(pk2(xs[k0i][tok], xs[k0i + 1][tok]),
                                pk2(xs[k0i + 2][tok], xs[k0i + 3][tok]),
                                pk2(xs[k0i + 4][tok], xs[k0i + 5][tok]),
                                pk2(xs[k0i + 6][tok], xs[k0i + 7][tok]));
    }
  }
  const int dbase = w << 7;
  #pragma unroll
  for (int dtl = 0; dtl < 8; ++dtl) {
    const uint16_t* ap = wqkvb + (size_t)(dbase + dtl * 16 + c) * 128 + g * 8;
    U a0, a1, a2, a3;
    a0.u = *(const uint4*)(ap);
    a1.u = *(const uint4*)(ap + 32);
    a2.u = *(const uint4*)(ap + 64);
    a3.u = *(const uint4*)(ap + 96);
    f32x4 acc0 = {0.f, 0.f, 0.f, 0.f}, acc1 = acc0;
    acc0 = __builtin_amdgcn_mfma_f32_16x16x32_bf16(a0.s, bf[0][0].s, acc0, 0, 0, 0);
    acc1 = __builtin_amdgcn_mfma_f32_16x16x32_bf16(a0.s, bf[1][0].s, acc1, 0, 0, 0);
    acc0 = __builtin_amdgcn_mfma_f32_16x16x32_bf16(a1.s, bf[0][1].s, acc0, 0, 0, 0);
    acc1 = __builtin_amdgcn_mfma_f32_16x16x32_bf16(a1.s, bf[1][1].s, acc1, 0, 0, 0);
    acc0 = __builtin_amdgcn_mfma_f32_16x16x32_bf16(a2.s, bf[0][2].s, acc0, 0, 0, 0);
    acc1 = __builtin_amdgcn_mfma_f32_16x16x32_bf16(a2.s, bf[1][2].s, acc1, 0, 0, 0);
    acc0 = __builtin_amdgcn_mfma_f32_16x16x32_bf16(a3.s, bf[0][3].s, acc0, 0, 0, 0);
    acc1 = __builtin_amdgcn_mfma_f32_16x16x32_bf16(a3.s, bf[1][3].s, acc1, 0, 0, 0);
    const int dl = dtl * 16 + g * 4;
    const float s0 = shq[dbase + dl], s1 = shq[dbase + dl + 1];
    const float s2 = shq[dbase + dl + 2], s3 = shq[dbase + dl + 3];
    *(uint32_t*)&ys[w][0][c][dl]     = pk2(acc0[0] + s0, acc0[1] + s1);
    *(uint32_t*)&ys[w][0][c][dl + 2] = pk2(acc0[2] + s2, acc0[3] + s3);
    *(uint32_t*)&ys[w][1][c][dl]     = pk2(acc1[0] + s0, acc1[1] + s1);
    *(uint32_t*)&ys[w][1][c][dl + 2] = pk2(acc1[2] + s2, acc1[3] + s3);
  }
  __syncthreads();
  const size_t bh = (size_t)(b * 4 + w);
  #pragma unroll
  for (int tt = 0; tt < 2; ++tt) {
    {  // K: dims 32..63 -> kws row-major
      const int tok = l >> 2, seg = l & 3;
      const uint16_t* yp = &ys[w][tt][tok][32 + seg * 8];
      *(uint4*)(kws + (bh * 1024 + n0 + tt * 16 + tok) * 32 + seg * 8) =
          make_uint4(*(const uint32_t*)(yp), *(const uint32_t*)(yp + 2),
                     *(const uint32_t*)(yp + 4), *(const uint32_t*)(yp + 6));
    }
    {  // Q: dims 0..31 -> qt transposed
      const int dq = l >> 1, half = l & 1;
      uint32_t qv[4];
      #pragma unroll
      for (int i = 0; i < 4; ++i) {
        const uint32_t a0 = ys[w][tt][half * 8 + 2 * i][dq];
        const uint32_t a1 = ys[w][tt][half * 8 + 2 * i + 1][dq];
        qv[i] = (a0 & 0xFFFFu) | (a1 << 16);
      }
      *(uint4*)(qt + bh * 32768 + (size_t)dq * 1024 + n0 + tt * 16 + half * 8) =
          make_uint4(qv[0], qv[1], qv[2], qv[3]);
    }
    {  // V: dims 64..127 -> sigma-permuted vt2
      const int cv = l & 15, gv = l >> 4;
      const int t32 = n0 >> 5;
      const int jb = tt * 4;
      #pragma unroll
      for (int dtv = 0; dtv < 4; ++dtv) {
        const uint32_t v0 = ys[w][tt][4 * gv + 0][64 + dtv * 16 + cv];
        const uint32_t v1 = ys[w][tt][4 * gv + 1][64 + dtv * 16 + cv];
        const uint32_t v2 = ys[w][tt][4 * gv + 2][64 + dtv * 16 + cv];
        const uint32_t v3 = ys[w][tt][4 * gv + 3][64 + dtv * 16 + cv];
        *(uint2*)(vt + bh * 65536 + (size_t)(t32 * 4 + dtv) * 512 + gv * 128 + cv * 8 + jb) =
            make_uint2((v0 & 0xFFFFu) | (v1 << 16), (v2 & 0xFFFFu) | (v3 << 16));
      }
    }
  }
}

// ---------------- K2: MFMA flash attention, 64 q/wave (4 q-sets share each K/V load) --------
// block = (b, h, 256 q); 4 waves x 64 q; per 32-key step: 6 uint4 loads, 24 MFMA, 32 exp2.
__global__ __launch_bounds__(256) void k2_attn(
    const uint16_t* __restrict__ qt, const uint16_t* __restrict__ kws,
    const uint16_t* __restrict__ vt, const float* __restrict__ ab,
    uint16_t* __restrict__ ob) {
  __shared__ float biasr[1024];
  __shared__ float osm[4][16][68];
  const int t = threadIdx.x;
  const int blk = ((blockIdx.x & 7) << 6) | (blockIdx.x >> 3);  // 512 blocks bijective
  const int qb = blk & 3, h = (blk >> 2) & 3, b = blk >> 4;
  for (int i = t; i < 1024; i += 256) biasr[i] = ab[(h << 10) + i] * L2E;
  __syncthreads();
  const int w = t >> 6, l = t & 63;
  const int c = l & 15, g = l >> 4;
  const int nqA = (qb << 8) + (w << 6) + c;  // sets: A=+0, B=+16, C=+32, D=+48
  const size_t bh = (size_t)(b * 4 + h);
  const uint16_t* qtb = qt + bh * 32768;
  const uint16_t* kp0 = kws + bh * 32768 + (size_t)c * 32 + (g << 3);
  const uint16_t* vp0 = vt + bh * 65536 + (size_t)l * 8;
  short8 qfA, qfB, qfC, qfD;
  #pragma unroll
  for (int j = 0; j < 8; ++j) {
    const uint16_t* qp = qtb + (size_t)((g << 3) + j) * 1024 + nqA;
    qfA[j] = (short)qp[0];
    qfB[j] = (short)qp[16];
    qfC[j] = (short)qp[32];
    qfD[j] = (short)qp[48];
  }
  const int qrowA = nqA >> 5;      // qcol(A,C)=c, qcol(B,D)=c+16; qrow(C,D)=qrowA+1
  int e[4], ae[4];
  #pragma unroll
  for (int r = 0; r < 4; ++r) { e[r] = (g << 2) + r - c; ae[r] = e[r] < 0 ? -e[r] : e[r]; }

  f32x4 zz = {0.f, 0.f, 0.f, 0.f};
  f32x4 o0A = zz, o1A = zz, o2A = zz, o3A = zz;
  f32x4 o0B = zz, o1B = zz, o2B = zz, o3B = zz;
  f32x4 o0C = zz, o1C = zz, o2C = zz, o3C = zz;
  f32x4 o0D = zz, o1D = zz, o2D = zz, o3D = zz;
  float lA = 0.f, lB = 0.f, lC = 0.f, lD = 0.f;

  union U { uint4 u; short8 s; };
  for (int ts = 0; ts < 32; ++ts) {
    U ka, kc;
    ka.u = *(const uint4*)(kp0 + (size_t)ts * 1024);
    kc.u = *(const uint4*)(kp0 + (size_t)ts * 1024 + 512);
    const uint16_t* vp = vp0 + (size_t)ts * 2048;
    U va, vb, vc, vd;
    va.u = *(const uint4*)(vp);
    vb.u = *(const uint4*)(vp + 512);
    vc.u = *(const uint4*)(vp + 1024);
    vd.u = *(const uint4*)(vp + 1536);

    const f32x4 z = {0.f, 0.f, 0.f, 0.f};
    f32x4 s0A = __builtin_amdgcn_mfma_f32_16x16x32_bf16(ka.s, qfA, z, 0, 0, 0);
    f32x4 s1A = __builtin_amdgcn_mfma_f32_16x16x32_bf16(kc.s, qfA, z, 0, 0, 0);
    f32x4 s0B = __builtin_amdgcn_mfma_f32_16x16x32_bf16(ka.s, qfB, z, 0, 0, 0);
    f32x4 s1B = __builtin_amdgcn_mfma_f32_16x16x32_bf16(kc.s, qfB, z, 0, 0, 0);
    f32x4 s0C = __builtin_amdgcn_mfma_f32_16x16x32_bf16(ka.s, qfC, z, 0, 0, 0);
    f32x4 s1C = __builtin_amdgcn_mfma_f32_16x16x32_bf16(kc.s, qfC, z, 0, 0, 0);
    f32x4 s0D = __builtin_amdgcn_mfma_f32_16x16x32_bf16(ka.s, qfD, z, 0, 0, 0);
    f32x4 s1D = __builtin_amdgcn_mfma_f32_16x16x32_bf16(kc.s, qfD, z, 0, 0, 0);

    int drA = qrowA - ts;     drA = drA < 0 ? -drA : drA;
    int drC = qrowA + 1 - ts; drC = drC < 0 ? -drC : drC;
    const float* browA = biasr + (drA << 5);
    const float* browC = biasr + (drC << 5);
    float pA[8], pB[8], pC[8], pD[8];
    float sA = 0.f, sB = 0.f, sC = 0.f, sD = 0.f;
    #pragma unroll
    for (int r = 0; r < 4; ++r) {
      const float a0 = browA[ae[r]];
      const float a1 = browA[16 + e[r]];
      const float a2 = browA[16 - e[r]];
      const float c0 = browC[ae[r]];
      const float c1 = browC[16 + e[r]];
      const float c2 = browC[16 - e[r]];
      pA[r]     = fexp2(fmaf(s0A[r], SCALE2, a0));
      pA[4 + r] = fexp2(fmaf(s1A[r], SCALE2, a1));
      pB[r]     = fexp2(fmaf(s0B[r], SCALE2, a2));
      pB[4 + r] = fexp2(fmaf(s1B[r], SCALE2, a0));
      pC[r]     = fexp2(fmaf(s0C[r], SCALE2, c0));
      pC[4 + r] = fexp2(fmaf(s1C[r], SCALE2, c1));
      pD[r]     = fexp2(fmaf(s0D[r], SCALE2, c2));
      pD[4 + r] = fexp2(fmaf(s1D[r], SCALE2, c0));
      sA += pA[r] + pA[4 + r];
      sB += pB[r] + pB[4 + r];
      sC += pC[r] + pC[4 + r];
      sD += pD[r] + pD[4 + r];
    }
    lA += sA; lB += sB; lC += sC; lD += sD;
    U pfA, pfB, pfC, pfD;
    pfA.u = make_uint4(pk2(pA[0], pA[1]), pk2(pA[2], pA[3]), pk2(pA[4], pA[5]), pk2(pA[6], pA[7]));
    pfB.u = make_uint4(pk2(pB[0], pB[1]), pk2(pB[2], pB[3]), pk2(pB[4], pB[5]), pk2(pB[6], pB[7]));
    pfC.u = make_uint4(pk2(pC[0], pC[1]), pk2(pC[2], pC[3]), pk2(pC[4], pC[5]), pk2(pC[6], pC[7]));
    pfD.u = make_uint4(pk2(pD[0], pD[1]), pk2(pD[2], pD[3]), pk2(pD[4], pD[5]), pk2(pD[6], pD[7]));

    o0A = __builtin_amdgcn_mfma_f32_16x16x32_bf16(va.s, pfA.s, o0A, 0, 0, 0);
    o1A = __builtin_amdgcn_mfma_f32_16x16x32_bf16(vb.s, pfA.s, o1A, 0, 0, 0);
    o2A = __builtin_amdgcn_mfma_f32_16x16x32_bf16(vc.s, pfA.s, o2A, 0, 0, 0);
    o3A = __builtin_amdgcn_mfma_f32_16x16x32_bf16(vd.s, pfA.s, o3A, 0, 0, 0);
    o0B = __builtin_amdgcn_mfma_f32_16x16x32_bf16(va.s, pfB.s, o0B, 0, 0, 0);
    o1B = __builtin_amdgcn_mfma_f32_16x16x32_bf16(vb.s, pfB.s, o1B, 0, 0, 0);
    o2B = __builtin_amdgcn_mfma_f32_16x16x32_bf16(vc.s, pfB.s, o2B, 0, 0, 0);
    o3B = __builtin_amdgcn_mfma_f32_16x16x32_bf16(vd.s, pfB.s, o3B, 0, 0, 0);
    o0C = __builtin_amdgcn_mfma_f32_16x16x32_bf16(va.s, pfC.s, o0C, 0, 0, 0);
    o1C = __builtin_amdgcn_mfma_f32_16x16x32_bf16(vb.s, pfC.s, o1C, 0, 0, 0);
    o2C = __builtin_amdgcn_mfma_f32_16x16x32_bf16(vc.s, pfC.s, o2C, 0, 0, 0);
    o3C = __builtin_amdgcn_mfma_f32_16x16x32_bf16(vd.s, pfC.s, o3C, 0, 0, 0);
    o0D = __builtin_amdgcn_mfma_f32_16x16x32_bf16(va.s, pfD.s, o0D, 0, 0, 0);
    o1D = __builtin_amdgcn_mfma_f32_16x16x32_bf16(vb.s, pfD.s, o1D, 0, 0, 0);
    o2D = __builtin_amdgcn_mfma_f32_16x16x32_bf16(vc.s, pfD.s, o2D, 0, 0, 0);
    o3D = __builtin_amdgcn_mfma_f32_16x16x32_bf16(vd.s, pfD.s, o3D, 0, 0, 0);
  }

  lA += __shfl_xor(lA, 16, 64); lA += __shfl_xor(lA, 32, 64);
  lB += __shfl_xor(lB, 16, 64); lB += __shfl_xor(lB, 32, 64);
  lC += __shfl_xor(lC, 16, 64); lC += __shfl_xor(lC, 32, 64);
  lD += __shfl_xor(lD, 16, 64); lD += __shfl_xor(lD, 32, 64);
  const float invA = 1.f / lA, invB = 1.f / lB, invC = 1.f / lC, invD = 1.f / lD;

  const int q2 = l >> 2, dg = l & 3;
  const int kkw = h * 2 + (dg >> 1);
  const int g0 = (dg & 1) * 2;
  #pragma unroll
  for (int set = 0; set < 4; ++set) {
    const float inv = set == 0 ? invA : set == 1 ? invB : set == 2 ? invC : invD;
    const f32x4 oo0 = set == 0 ? o0A : set == 1 ? o0B : set == 2 ? o0C : o0D;
    const f32x4 oo1 = set == 0 ? o1A : set == 1 ? o1B : set == 2 ? o1C : o1D;
    const f32x4 oo2 = set == 0 ? o2A : set == 1 ? o2B : set == 2 ? o2C : o2D;
    const f32x4 oo3 = set == 0 ? o3A : set == 1 ? o3B : set == 2 ? o3C : o3D;
    #pragma unroll
    for (int i = 0; i < 4; ++i) {
      osm[w][c][(g << 2) + i]      = oo0[i] * inv;
      osm[w][c][16 + (g << 2) + i] = oo1[i] * inv;
      osm[w][c][32 + (g << 2) + i] = oo2[i] * inv;
      osm[w][c][48 + (g << 2) + i] = oo3[i] * inv;
    }
    __syncthreads();
    float ov[16];
    #pragma unroll
    for (int i = 0; i < 16; i += 4) {
      const float4 rr = *(const float4*)&osm[w][q2][dg * 16 + i];
      ov[i] = rr.x; ov[i + 1] = rr.y; ov[i + 2] = rr.z; ov[i + 3] = rr.w;
    }
    uint32_t pkd[8];
    #pragma unroll
    for (int i = 0; i < 8; ++i) pkd[i] = pk2(clip1(ov[2 * i]), clip1(ov[2 * i + 1]));
    const int t16 = (qb << 4) + (w << 2) + set;
    uint16_t* opb = ob + (((size_t)(b * 64 + t16) * 8 + kkw) << 9);
    *(uint4*)(opb + (g0 * 16 + q2) * 8)       = make_uint4(pkd[0], pkd[1], pkd[2], pkd[3]);
    *(uint4*)(opb + ((g0 + 1) * 16 + q2) * 8) = make_uint4(pkd[4], pkd[5], pkd[6], pkd[7]);
    __syncthreads();
  }
}

// ---------------- K345: fused proj + MLP, LDS-staged weights via async global_load_lds ------
__global__ __launch_bounds__(256) void k345_mlp(
    const uint16_t* __restrict__ ob, const float* __restrict__ x,
    const uint16_t* __restrict__ wpb, const float* __restrict__ shp,
    const uint16_t* __restrict__ w1p, const float* __restrict__ sh1,
    const uint16_t* __restrict__ w2p, const float* __restrict__ sh2,
    float* __restrict__ out) {
  __shared__ uint16_t wl[32768];  // 64 KB, reused across 3 phases
  const int t = threadIdx.x;
  const int b = blockIdx.x >> 4, n0 = (blockIdx.x & 15) << 6;
  const int w = t >> 6, l = t & 63, c = l & 15, g = l >> 4;
  const int tw = n0 + (w << 4) + c;
  const int lo = c * 32 + g * 8;       // lane offset within a 512-element tile
  const int wb = (w << 6) * 8;         // wave-uniform LDS element base (w*512)
  union U { uint4 u; short8 s; };
  // ---- phase 1: async-stage proj weights; load ob fragments while they fly ----
  #pragma unroll
  for (int it = 0; it < 16; ++it)
    async_cp16(wpb + it * 2048 + t * 8, &wl[it * 2048 + wb]);
  U bf[8];
  const int t16 = (n0 >> 4) + w;
  const uint16_t* op = ob + (((size_t)(b * 64 + t16) * 8) << 9) + l * 8;
  #pragma unroll
  for (int kk = 0; kk < 8; ++kk) bf[kk].u = *(const uint4*)(op + kk * 512);
  __syncthreads();
  // ---- proj: x1 = x + BN(ob @ Wp^T) ----
  float vr[8][4];
  #pragma unroll
  for (int dt = 0; dt < 8; ++dt) {
    f32x4 acc = {0.f, 0.f, 0.f, 0.f};
    #pragma unroll
    for (int kk = 0; kk < 8; ++kk) {
      U a; a.u = *(const uint4*)&wl[(dt * 8 + kk) * 512 + lo];
      acc = __builtin_amdgcn_mfma_f32_16x16x32_bf16(a.s, bf[kk].s, acc, 0, 0, 0);
    }
    #pragma unroll
    for (int r = 0; r < 4; ++r) {
      const int d = dt * 16 + g * 4 + r;
      vr[dt][r] = acc[r] + shp[d] + x[((size_t)b * 128 + d) * 1024 + tw];
    }
  }
  __syncthreads();  // all waves done reading proj weights
  // ---- phase 2: async-stage W1; build xf while it flies ----
  #pragma unroll
  for (int it = 0; it < 16; ++it)
    async_cp16(w1p + it * 2048 + t * 8, &wl[it * 2048 + wb]);
  U xf[4];
  #pragma unroll
  for (int kk = 0; kk < 4; ++kk)
    xf[kk].u = make_uint4(pk2(vr[2 * kk][0], vr[2 * kk][1]), pk2(vr[2 * kk][2], vr[2 * kk][3]),
                          pk2(vr[2 * kk + 1][0], vr[2 * kk + 1][1]), pk2(vr[2 * kk + 1][2], vr[2 * kk + 1][3]));
  __syncthreads();
  // ---- MLP1 (w1p tiles [d1t*4+kk]) ----
  U pf[8];
  #pragma unroll
  for (int kk2 = 0; kk2 < 8; ++kk2) {
    f32x4 aa = {0.f, 0.f, 0.f, 0.f}, bb = aa;
    #pragma unroll
    for (int kk = 0; kk < 4; ++kk) {
      U a; a.u = *(const uint4*)&wl[((2 * kk2) * 4 + kk) * 512 + lo];
      aa = __builtin_amdgcn_mfma_f32_16x16x32_bf16(a.s, xf[kk].s, aa, 0, 0, 0);
    }
    #pragma unroll
    for (int kk = 0; kk < 4; ++kk) {
      U a; a.u = *(const uint4*)&wl[((2 * kk2 + 1) * 4 + kk) * 512 + lo];
      bb = __builtin_amdgcn_mfma_f32_16x16x32_bf16(a.s, xf[kk].s, bb, 0, 0, 0);
    }
    float ha[4], hb[4];
    #pragma unroll
    for (int r = 0; r < 4; ++r) {
      ha[r] = clip1(aa[r] + sh1[(2 * kk2) * 16 + g * 4 + r]);
      hb[r] = clip1(bb[r] + sh1[(2 * kk2 + 1) * 16 + g * 4 + r]);
    }
    pf[kk2].u = make_uint4(pk2(ha[0], ha[1]), pk2(ha[2], ha[3]), pk2(hb[0], hb[1]), pk2(hb[2], hb[3]));
  }
  __syncthreads();  // all waves done reading W1
  // ---- phase 3: async-stage W2 ----
  #pragma unroll
  for (int it = 0; it < 16; ++it)
    async_cp16(w2p + it * 2048 + t * 8, &wl[it * 2048 + wb]);
  __syncthreads();
  // ---- MLP2 + residual ----
  #pragma unroll
  for (int d2t = 0; d2t < 8; ++d2t) {
    f32x4 acc = {0.f, 0.f, 0.f, 0.f};
    #pragma unroll
    for (int kk2 = 0; kk2 < 8; ++kk2) {
      U a; a.u = *(const uint4*)&wl[(d2t * 8 + kk2) * 512 + lo];
      acc = __builtin_amdgcn_mfma_f32_16x16x32_bf16(a.s, pf[kk2].s, acc, 0, 0, 0);
    }
    #pragma unroll
    for (int r = 0; r < 4; ++r) {
      const int d = d2t * 16 + g * 4 + r;
      out[((size_t)b * 128 + d) * 1024 + tw] = acc[r] + sh2[d] + vr[d2t][r];
    }
  }
}

}  // namespace

extern "C" void kernel_launch(void* const* d_in, const int* in_sizes, int n_in,
                              void* d_out, int out_size, void* d_ws, size_t ws_size,
                              hipStream_t stream) {
  const float* x  = (const float*)d_in[0];
  const float* Wq = (const float*)d_in[1];
  const float* gq = (const float*)d_in[2];
  const float* bq = (const float*)d_in[3];
  const float* mq = (const float*)d_in[4];
  const float* vq = (const float*)d_in[5];
  const float* Wp = (const float*)d_in[6];
  const float* gp = (const float*)d_in[7];
  const float* bp = (const float*)d_in[8];
  const float* mp = (const float*)d_in[9];
  const float* vp = (const float*)d_in[10];
  const float* W1 = (const float*)d_in[11];
  const float* g1 = (const float*)d_in[12];
  const float* b1 = (const float*)d_in[13];
  const float* m1 = (const float*)d_in[14];
  const float* v1 = (const float*)d_in[15];
  const float* W2 = (const float*)d_in[16];
  const float* g2 = (const float*)d_in[17];
  const float* b2 = (const float*)d_in[18];
  const float* m2 = (const float*)d_in[19];
  const float* v2 = (const float*)d_in[20];
  const float* ab = (const float*)d_in[21];
  float* out = (float*)d_out;

  char* ws = (char*)d_ws;
  uint16_t* qt   = (uint16_t*)(ws);                 // 8 MiB  [bh][32][1024]
  uint16_t* kwsp = (uint16_t*)(ws + (8ull << 20));  // 8 MiB  [bh][1024][32]
  uint16_t* vt   = (uint16_t*)(ws + (16ull << 20)); // 16 MiB sigma-permuted
  uint16_t* obuf = (uint16_t*)(ws + (32ull << 20)); // 16 MiB clip(o) bf16, fragment-native ob2
  uint16_t* wqkvb = (uint16_t*)(ws + (48ull << 20));
  uint16_t* wpb   = wqkvb + 65536;
  uint16_t* w1p   = wpb + 32768;
  uint16_t* w2p   = w1p + 32768;
  float* shq = (float*)(w2p + 32768);
  float* shp = shq + 512;
  float* sh1 = shp + 128;
  float* sh2 = sh1 + 256;

  k0_fold<<<644, 256, 0, stream>>>(Wq, gq, bq, mq, vq, Wp, gp, bp, mp, vp,
                                   W1, g1, b1, m1, v1, W2, g2, b2, m2, v2,
                                   wqkvb, shq, wpb, shp, w1p, sh1, w2p, sh2);
  k1_qkv<<<1024, 256, 0, stream>>>(x, wqkvb, shq, qt, kwsp, vt);
  k2_attn<<<512, 256, 0, stream>>>(qt, kwsp, vt, ab, obuf);
  k345_mlp<<<512, 256, 0, stream>>>(obuf, x, wpb, shp, w1p, sh1, w2p, sh2, out);
  (void)in_sizes; (void)n_in; (void)out_size; (void)ws_size;
}

// Round 18
// 96.826 us; speedup vs baseline: 1.1191x; 1.1191x over previous
//
#include <hip/hip_runtime.h>
#include <hip/hip_bf16.h>
#include <stdint.h>

namespace {

constexpr float EPSF = 1e-5f;
constexpr float L2E = 1.4426950408889634f;
constexpr float QK_SCALE = 0.17677669529663687f;  // 32^-0.5
constexpr float SCALE2 = QK_SCALE * L2E;          // folded for exp2

typedef __attribute__((ext_vector_type(8))) short short8;
typedef __attribute__((ext_vector_type(4))) float f32x4;

#if __has_builtin(__builtin_amdgcn_exp2f)
__device__ __forceinline__ float fexp2(float x) { return __builtin_amdgcn_exp2f(x); }
#else
__device__ __forceinline__ float fexp2(float x) { return __expf(x * 0.6931471805599453f); }
#endif

__device__ __forceinline__ uint32_t pk2(float a, float b) {  // RNE pair -> v_cvt_pk_bf16_f32
  union { __hip_bfloat162 h; uint32_t u; } cv;
  cv.h.x = __float2bfloat16(a);
  cv.h.y = __float2bfloat16(b);
  return cv.u;
}
__device__ __forceinline__ uint16_t bf1(float f) {
  union { __hip_bfloat16 h; uint16_t u; } cv;
  cv.h = __float2bfloat16(f);
  return cv.u;
}
__device__ __forceinline__ float clip1(float v) { return fminf(fmaxf(v, -1.f), 1.f); }

// async global->LDS copy, 16B per lane; lds base must be wave-uniform.
__device__ __forceinline__ void async_cp16(const uint16_t* g, uint16_t* l) {
  __builtin_amdgcn_global_load_lds(
      (const __attribute__((address_space(1))) uint32_t*)g,
      (__attribute__((address_space(3))) uint32_t*)l, 16, 0, 0);
}

// ---------------- K0: fold BN scales into bf16 weights, fragment-tile layouts ----------------
// wqkvb[512][128] row-major (k1).
// For k345 (LDS-staged), tile layout [tile][c:16][g:4][jj:8]:
//   wpb2[dt*8+kk][c][g][jj] = Wpfold[dt*16+c][kk*32 + g*8 + jj]            (dt<8, kk<8)
//   w1p2[d1t*4+kk][c][g][jj] = W1fold[d1t*16+c][kk*32 + sigma(g,jj)]      (d1t<16, kk<4)
//   w2p2[d2t*8+kk2][c][g][jj] = W2fold[d2t*16+c][kk2*32 + sigma(g,jj)]    (d2t<8, kk2<8)
// sigma(g,j) = j<4 ? 4g+j : 16+4g+(j-4)
__global__ void k0_fold(
    const float* __restrict__ Wq, const float* __restrict__ gq, const float* __restrict__ bq,
    const float* __restrict__ mq, const float* __restrict__ vq,
    const float* __restrict__ Wp, const float* __restrict__ gp, const float* __restrict__ bp,
    const float* __restrict__ mp, const float* __restrict__ vp,
    const float* __restrict__ W1, const float* __restrict__ g1, const float* __restrict__ b1,
    const float* __restrict__ m1, const float* __restrict__ v1,
    const float* __restrict__ W2, const float* __restrict__ g2, const float* __restrict__ b2,
    const float* __restrict__ m2, const float* __restrict__ v2,
    uint16_t* __restrict__ wqkvb, float* __restrict__ shq,
    uint16_t* __restrict__ wpb, float* __restrict__ shp,
    uint16_t* __restrict__ w1p, float* __restrict__ sh1,
    uint16_t* __restrict__ w2p, float* __restrict__ sh2) {
  int id = blockIdx.x * 256 + threadIdx.x;
  if (id < 65536) {
    int d = id >> 7;
    wqkvb[id] = bf1(Wq[id] * (gq[d] * rsqrtf(vq[d] + EPSF)));
  } else if (id < 98304) {
    int j = id - 65536;
    int jj = j & 7, g = (j >> 3) & 3, cc = (j >> 5) & 15, kk = (j >> 9) & 7, dt = (j >> 12) & 7;
    int row = dt * 16 + cc;
    int col = kk * 32 + g * 8 + jj;
    wpb[j] = bf1(Wp[row * 256 + col] * (gp[row] * rsqrtf(vp[row] + EPSF)));
  } else if (id < 131072) {
    int j = id - 98304;
    int jj = j & 7, g = (j >> 3) & 3, cc = (j >> 5) & 15, kk = (j >> 9) & 3, d1t = (j >> 11) & 15;
    int row = d1t * 16 + cc;
    int col = kk * 32 + (jj < 4 ? 4 * g + jj : 16 + 4 * g + (jj - 4));
    w1p[j] = bf1(W1[row * 128 + col] * (g1[row] * rsqrtf(v1[row] + EPSF)));
  } else if (id < 163840) {
    int j = id - 131072;
    int jj = j & 7, g = (j >> 3) & 3, cc = (j >> 5) & 15, kk2 = (j >> 9) & 7, d2t = (j >> 12) & 7;
    int row = d2t * 16 + cc;
    int col = kk2 * 32 + (jj < 4 ? 4 * g + jj : 16 + 4 * g + (jj - 4));
    w2p[j] = bf1(W2[row * 256 + col] * (g2[row] * rsqrtf(v2[row] + EPSF)));
  } else if (id < 164864) {
    int j = id - 163840;
    if (j < 512)      shq[j] = bq[j] - mq[j] * (gq[j] * rsqrtf(vq[j] + EPSF));
    else if (j < 640) { int d = j - 512; shp[d] = bp[d] - mp[d] * (gp[d] * rsqrtf(vp[d] + EPSF)); }
    else if (j < 896) { int d = j - 640; sh1[d] = b1[d] - m1[d] * (g1[d] * rsqrtf(v1[d] + EPSF)); }
    else              { int d = j - 896; sh2[d] = b2[d] - m2[d] * (g2[d] * rsqrtf(v2[d] + EPSF)); }
  }
}

// ---------------- K1: MFMA qkv = BN(x_in @ Wqkv^T) -> qt / kws / vt2, bf16 (R11 version) ----
__global__ __launch_bounds__(256) void k1_qkv(
    const float* __restrict__ x, const uint16_t* __restrict__ wqkvb, const float* __restrict__ shq,
    uint16_t* __restrict__ qt, uint16_t* __restrict__ kws, uint16_t* __restrict__ vt) {
  __shared__ float xs[128][36];
  __shared__ uint16_t ys[4][2][16][136];
  const int t = threadIdx.x;
  const int blk = ((blockIdx.x & 7) << 7) | (blockIdx.x >> 3);  // 1024 bijective XCD chunks
  const int b = blk >> 5, n0 = (blk & 31) << 5;
  {
    const int row = t >> 1, col = (t & 1) << 4;
    const float* xp = x + (size_t)b * (128 * 1024) + (size_t)row * 1024 + n0 + col;
    *(float4*)&xs[row][col]      = *(const float4*)xp;
    *(float4*)&xs[row][col + 4]  = *(const float4*)(xp + 4);
    *(float4*)&xs[row][col + 8]  = *(const float4*)(xp + 8);
    *(float4*)&xs[row][col + 12] = *(const float4*)(xp + 12);
  }
  __syncthreads();
  const int w = t >> 6, l = t & 63, c = l & 15, g = l >> 4;
  union U { uint4 u; short8 s; };
  U bf[2][4];
  #pragma unroll
  for (int tt = 0; tt < 2; ++tt) {
    const int tok = tt * 16 + c;
    #pragma unroll
    for (int kk = 0; kk < 4; ++kk) {
      const int k0i = kk * 32 + g * 8;
      bf[tt][kk].u = make_uint4(pk2(xs[k0i][tok], xs[k0i + 1][tok]),
                                pk2(xs[k0i + 2][tok], xs[k0i + 3][tok]),
                                pk2(xs[k0i + 4][tok], xs[k0i + 5][tok]),
                                pk2(xs[k0i + 6][tok], xs[k0i + 7][tok]));
    }
  }
  const int dbase = w << 7;
  #pragma unroll
  for (int dtl = 0; dtl < 8; ++dtl) {
    const uint16_t* ap = wqkvb + (size_t)(dbase + dtl * 16 + c) * 128 + g * 8;
    U a0, a1, a2, a3;
    a0.u = *(const uint4*)(ap);
    a1.u = *(const uint4*)(ap + 32);
    a2.u = *(const uint4*)(ap + 64);
    a3.u = *(const uint4*)(ap + 96);
    f32x4 acc0 = {0.f, 0.f, 0.f, 0.f}, acc1 = acc0;
    acc0 = __builtin_amdgcn_mfma_f32_16x16x32_bf16(a0.s, bf[0][0].s, acc0, 0, 0, 0);
    acc1 = __builtin_amdgcn_mfma_f32_16x16x32_bf16(a0.s, bf[1][0].s, acc1, 0, 0, 0);
    acc0 = __builtin_amdgcn_mfma_f32_16x16x32_bf16(a1.s, bf[0][1].s, acc0, 0, 0, 0);
    acc1 = __builtin_amdgcn_mfma_f32_16x16x32_bf16(a1.s, bf[1][1].s, acc1, 0, 0, 0);
    acc0 = __builtin_amdgcn_mfma_f32_16x16x32_bf16(a2.s, bf[0][2].s, acc0, 0, 0, 0);
    acc1 = __builtin_amdgcn_mfma_f32_16x16x32_bf16(a2.s, bf[1][2].s, acc1, 0, 0, 0);
    acc0 = __builtin_amdgcn_mfma_f32_16x16x32_bf16(a3.s, bf[0][3].s, acc0, 0, 0, 0);
    acc1 = __builtin_amdgcn_mfma_f32_16x16x32_bf16(a3.s, bf[1][3].s, acc1, 0, 0, 0);
    const int dl = dtl * 16 + g * 4;
    const float s0 = shq[dbase + dl], s1 = shq[dbase + dl + 1];
    const float s2 = shq[dbase + dl + 2], s3 = shq[dbase + dl + 3];
    *(uint32_t*)&ys[w][0][c][dl]     = pk2(acc0[0] + s0, acc0[1] + s1);
    *(uint32_t*)&ys[w][0][c][dl + 2] = pk2(acc0[2] + s2, acc0[3] + s3);
    *(uint32_t*)&ys[w][1][c][dl]     = pk2(acc1[0] + s0, acc1[1] + s1);
    *(uint32_t*)&ys[w][1][c][dl + 2] = pk2(acc1[2] + s2, acc1[3] + s3);
  }
  __syncthreads();
  const size_t bh = (size_t)(b * 4 + w);
  #pragma unroll
  for (int tt = 0; tt < 2; ++tt) {
    {  // K: dims 32..63 -> kws row-major
      const int tok = l >> 2, seg = l & 3;
      const uint16_t* yp = &ys[w][tt][tok][32 + seg * 8];
      *(uint4*)(kws + (bh * 1024 + n0 + tt * 16 + tok) * 32 + seg * 8) =
          make_uint4(*(const uint32_t*)(yp), *(const uint32_t*)(yp + 2),
                     *(const uint32_t*)(yp + 4), *(const uint32_t*)(yp + 6));
    }
    {  // Q: dims 0..31 -> qt transposed
      const int dq = l >> 1, half = l & 1;
      uint32_t qv[4];
      #pragma unroll
      for (int i = 0; i < 4; ++i) {
        const uint32_t a0 = ys[w][tt][half * 8 + 2 * i][dq];
        const uint32_t a1 = ys[w][tt][half * 8 + 2 * i + 1][dq];
        qv[i] = (a0 & 0xFFFFu) | (a1 << 16);
      }
      *(uint4*)(qt + bh * 32768 + (size_t)dq * 1024 + n0 + tt * 16 + half * 8) =
          make_uint4(qv[0], qv[1], qv[2], qv[3]);
    }
    {  // V: dims 64..127 -> sigma-permuted vt2
      const int cv = l & 15, gv = l >> 4;
      const int t32 = n0 >> 5;
      const int jb = tt * 4;
      #pragma unroll
      for (int dtv = 0; dtv < 4; ++dtv) {
        const uint32_t v0 = ys[w][tt][4 * gv + 0][64 + dtv * 16 + cv];
        const uint32_t v1 = ys[w][tt][4 * gv + 1][64 + dtv * 16 + cv];
        const uint32_t v2 = ys[w][tt][4 * gv + 2][64 + dtv * 16 + cv];
        const uint32_t v3 = ys[w][tt][4 * gv + 3][64 + dtv * 16 + cv];
        *(uint2*)(vt + bh * 65536 + (size_t)(t32 * 4 + dtv) * 512 + gv * 128 + cv * 8 + jb) =
            make_uint2((v0 & 0xFFFFu) | (v1 << 16), (v2 & 0xFFFFu) | (v3 << 16));
      }
    }
  }
}

// ---------------- K2: MFMA flash attention, 32 q/wave (R13 core, no setprio) ----------------
__global__ __launch_bounds__(256) void k2_attn(
    const uint16_t* __restrict__ qt, const uint16_t* __restrict__ kws,
    const uint16_t* __restrict__ vt, const float* __restrict__ ab,
    uint16_t* __restrict__ ob) {
  __shared__ float biasr[1024];
  __shared__ float osm[4][16][68];
  const int t = threadIdx.x;
  const int blk = ((blockIdx.x & 7) << 7) | (blockIdx.x >> 3);  // 1024 blocks bijective
  const int qb = blk & 7, h = (blk >> 3) & 3, b = blk >> 5;
  for (int i = t; i < 1024; i += 256) biasr[i] = ab[(h << 10) + i] * L2E;
  __syncthreads();
  const int w = t >> 6, l = t & 63;
  const int c = l & 15, g = l >> 4;
  const int nqA = (qb << 7) + (w << 5) + c;
  const size_t bh = (size_t)(b * 4 + h);
  const uint16_t* qtb = qt + bh * (32 * 1024);
  const uint16_t* kp0 = kws + bh * (1024 * 32) + (size_t)c * 32 + (g << 3);
  const uint16_t* vp0 = vt + bh * 65536 + (size_t)l * 8;
  short8 qfA, qfB;
  #pragma unroll
  for (int j = 0; j < 8; ++j) {
    qfA[j] = (short)qtb[(size_t)((g << 3) + j) * 1024 + nqA];
    qfB[j] = (short)qtb[(size_t)((g << 3) + j) * 1024 + nqA + 16];
  }
  const int qrow = nqA >> 5;
  int e[4], ae[4];
  #pragma unroll
  for (int r = 0; r < 4; ++r) { e[r] = (g << 2) + r - c; ae[r] = e[r] < 0 ? -e[r] : e[r]; }

  f32x4 o0A = {0.f, 0.f, 0.f, 0.f}, o1A = o0A, o2A = o0A, o3A = o0A;
  f32x4 o0B = o0A, o1B = o0A, o2B = o0A, o3B = o0A;
  float lA = 0.f, lB = 0.f;

  union U { uint4 u; short8 s; };
  for (int ts = 0; ts < 32; ++ts) {
    U ka, kc;
    ka.u = *(const uint4*)(kp0 + (size_t)ts * 1024);
    kc.u = *(const uint4*)(kp0 + (size_t)ts * 1024 + 512);
    const uint16_t* vp = vp0 + (size_t)ts * 2048;
    U va, vb, vc, vd;
    va.u = *(const uint4*)(vp);
    vb.u = *(const uint4*)(vp + 512);
    vc.u = *(const uint4*)(vp + 1024);
    vd.u = *(const uint4*)(vp + 1536);

    const f32x4 z = {0.f, 0.f, 0.f, 0.f};
    f32x4 s0A = __builtin_amdgcn_mfma_f32_16x16x32_bf16(ka.s, qfA, z, 0, 0, 0);
    f32x4 s1A = __builtin_amdgcn_mfma_f32_16x16x32_bf16(kc.s, qfA, z, 0, 0, 0);
    f32x4 s0B = __builtin_amdgcn_mfma_f32_16x16x32_bf16(ka.s, qfB, z, 0, 0, 0);
    f32x4 s1B = __builtin_amdgcn_mfma_f32_16x16x32_bf16(kc.s, qfB, z, 0, 0, 0);

    int dr = qrow - ts; dr = dr < 0 ? -dr : dr;
    const float* brow = biasr + (dr << 5);
    float pA[8], pB[8];
    float sA = 0.f, sB = 0.f;
    #pragma unroll
    for (int r = 0; r < 4; ++r) {
      const float b0 = brow[ae[r]];
      const float b1 = brow[16 + e[r]];
      const float b2 = brow[16 - e[r]];
      pA[r]     = fexp2(fmaf(s0A[r], SCALE2, b0));
      pA[4 + r] = fexp2(fmaf(s1A[r], SCALE2, b1));
      pB[r]     = fexp2(fmaf(s0B[r], SCALE2, b2));
      pB[4 + r] = fexp2(fmaf(s1B[r], SCALE2, b0));
      sA += pA[r] + pA[4 + r];
      sB += pB[r] + pB[4 + r];
    }
    lA += sA; lB += sB;
    U pfA, pfB;
    pfA.u = make_uint4(pk2(pA[0], pA[1]), pk2(pA[2], pA[3]), pk2(pA[4], pA[5]), pk2(pA[6], pA[7]));
    pfB.u = make_uint4(pk2(pB[0], pB[1]), pk2(pB[2], pB[3]), pk2(pB[4], pB[5]), pk2(pB[6], pB[7]));

    o0A = __builtin_amdgcn_mfma_f32_16x16x32_bf16(va.s, pfA.s, o0A, 0, 0, 0);
    o1A = __builtin_amdgcn_mfma_f32_16x16x32_bf16(vb.s, pfA.s, o1A, 0, 0, 0);
    o2A = __builtin_amdgcn_mfma_f32_16x16x32_bf16(vc.s, pfA.s, o2A, 0, 0, 0);
    o3A = __builtin_amdgcn_mfma_f32_16x16x32_bf16(vd.s, pfA.s, o3A, 0, 0, 0);
    o0B = __builtin_amdgcn_mfma_f32_16x16x32_bf16(va.s, pfB.s, o0B, 0, 0, 0);
    o1B = __builtin_amdgcn_mfma_f32_16x16x32_bf16(vb.s, pfB.s, o1B, 0, 0, 0);
    o2B = __builtin_amdgcn_mfma_f32_16x16x32_bf16(vc.s, pfB.s, o2B, 0, 0, 0);
    o3B = __builtin_amdgcn_mfma_f32_16x16x32_bf16(vd.s, pfB.s, o3B, 0, 0, 0);
  }

  lA += __shfl_xor(lA, 16, 64); lA += __shfl_xor(lA, 32, 64);
  lB += __shfl_xor(lB, 16, 64); lB += __shfl_xor(lB, 32, 64);
  const float invA = 1.f / lA, invB = 1.f / lB;

  const int q2 = l >> 2, dg = l & 3;
  const int kkw = h * 2 + (dg >> 1);
  const int g0 = (dg & 1) * 2;
  #pragma unroll
  for (int half = 0; half < 2; ++half) {
    const float inv = half ? invB : invA;
    const f32x4 oo0 = half ? o0B : o0A, oo1 = half ? o1B : o1A;
    const f32x4 oo2 = half ? o2B : o2A, oo3 = half ? o3B : o3A;
    #pragma unroll
    for (int i = 0; i < 4; ++i) {
      osm[w][c][(g << 2) + i]      = oo0[i] * inv;
      osm[w][c][16 + (g << 2) + i] = oo1[i] * inv;
      osm[w][c][32 + (g << 2) + i] = oo2[i] * inv;
      osm[w][c][48 + (g << 2) + i] = oo3[i] * inv;
    }
    __syncthreads();
    float ov[16];
    #pragma unroll
    for (int i = 0; i < 16; i += 4) {
      const float4 rr = *(const float4*)&osm[w][q2][dg * 16 + i];
      ov[i] = rr.x; ov[i + 1] = rr.y; ov[i + 2] = rr.z; ov[i + 3] = rr.w;
    }
    uint32_t pkd[8];
    #pragma unroll
    for (int i = 0; i < 8; ++i) pkd[i] = pk2(clip1(ov[2 * i]), clip1(ov[2 * i + 1]));
    const int t16 = (qb << 3) + (w << 1) + half;
    uint16_t* opb = ob + (((size_t)(b * 64 + t16) * 8 + kkw) << 9);
    *(uint4*)(opb + (g0 * 16 + q2) * 8)       = make_uint4(pkd[0], pkd[1], pkd[2], pkd[3]);
    *(uint4*)(opb + ((g0 + 1) * 16 + q2) * 8) = make_uint4(pkd[4], pkd[5], pkd[6], pkd[7]);
    __syncthreads();
  }
}

// ---------------- K345: fused proj + MLP, LDS-staged weights via async global_load_lds ------
__global__ __launch_bounds__(256) void k345_mlp(
    const uint16_t* __restrict__ ob, const float* __restrict__ x,
    const uint16_t* __restrict__ wpb, const float* __restrict__ shp,
    const uint16_t* __restrict__ w1p, const float* __restrict__ sh1,
    const uint16_t* __restrict__ w2p, const float* __restrict__ sh2,
    float* __restrict__ out) {
  __shared__ uint16_t wl[32768];  // 64 KB, reused across 3 phases
  const int t = threadIdx.x;
  const int b = blockIdx.x >> 4, n0 = (blockIdx.x & 15) << 6;
  const int w = t >> 6, l = t & 63, c = l & 15, g = l >> 4;
  const int tw = n0 + (w << 4) + c;
  const int lo = c * 32 + g * 8;       // lane offset within a 512-element tile
  const int wb = (w << 6) * 8;         // wave-uniform LDS element base (w*512)
  union U { uint4 u; short8 s; };
  // ---- phase 1: async-stage proj weights; load ob fragments while they fly ----
  #pragma unroll
  for (int it = 0; it < 16; ++it)
    async_cp16(wpb + it * 2048 + t * 8, &wl[it * 2048 + wb]);
  U bf[8];
  const int t16 = (n0 >> 4) + w;
  const uint16_t* op = ob + (((size_t)(b * 64 + t16) * 8) << 9) + l * 8;
  #pragma unroll
  for (int kk = 0; kk < 8; ++kk) bf[kk].u = *(const uint4*)(op + kk * 512);
  __syncthreads();
  // ---- proj: x1 = x + BN(ob @ Wp^T) ----
  float vr[8][4];
  #pragma unroll
  for (int dt = 0; dt < 8; ++dt) {
    f32x4 acc = {0.f, 0.f, 0.f, 0.f};
    #pragma unroll
    for (int kk = 0; kk < 8; ++kk) {
      U a; a.u = *(const uint4*)&wl[(dt * 8 + kk) * 512 + lo];
      acc = __builtin_amdgcn_mfma_f32_16x16x32_bf16(a.s, bf[kk].s, acc, 0, 0, 0);
    }
    #pragma unroll
    for (int r = 0; r < 4; ++r) {
      const int d = dt * 16 + g * 4 + r;
      vr[dt][r] = acc[r] + shp[d] + x[((size_t)b * 128 + d) * 1024 + tw];
    }
  }
  __syncthreads();  // all waves done reading proj weights
  // ---- phase 2: async-stage W1; build xf while it flies ----
  #pragma unroll
  for (int it = 0; it < 16; ++it)
    async_cp16(w1p + it * 2048 + t * 8, &wl[it * 2048 + wb]);
  U xf[4];
  #pragma unroll
  for (int kk = 0; kk < 4; ++kk)
    xf[kk].u = make_uint4(pk2(vr[2 * kk][0], vr[2 * kk][1]), pk2(vr[2 * kk][2], vr[2 * kk][3]),
                          pk2(vr[2 * kk + 1][0], vr[2 * kk + 1][1]), pk2(vr[2 * kk + 1][2], vr[2 * kk + 1][3]));
  __syncthreads();
  // ---- MLP1 (w1p tiles [d1t*4+kk]) ----
  U pf[8];
  #pragma unroll
  for (int kk2 = 0; kk2 < 8; ++kk2) {
    f32x4 aa = {0.f, 0.f, 0.f, 0.f}, bb = aa;
    #pragma unroll
    for (int kk = 0; kk < 4; ++kk) {
      U a; a.u = *(const uint4*)&wl[((2 * kk2) * 4 + kk) * 512 + lo];
      aa = __builtin_amdgcn_mfma_f32_16x16x32_bf16(a.s, xf[kk].s, aa, 0, 0, 0);
    }
    #pragma unroll
    for (int kk = 0; kk < 4; ++kk) {
      U a; a.u = *(const uint4*)&wl[((2 * kk2 + 1) * 4 + kk) * 512 + lo];
      bb = __builtin_amdgcn_mfma_f32_16x16x32_bf16(a.s, xf[kk].s, bb, 0, 0, 0);
    }
    float ha[4], hb[4];
    #pragma unroll
    for (int r = 0; r < 4; ++r) {
      ha[r] = clip1(aa[r] + sh1[(2 * kk2) * 16 + g * 4 + r]);
      hb[r] = clip1(bb[r] + sh1[(2 * kk2 + 1) * 16 + g * 4 + r]);
    }
    pf[kk2].u = make_uint4(pk2(ha[0], ha[1]), pk2(ha[2], ha[3]), pk2(hb[0], hb[1]), pk2(hb[2], hb[3]));
  }
  __syncthreads();  // all waves done reading W1
  // ---- phase 3: async-stage W2 ----
  #pragma unroll
  for (int it = 0; it < 16; ++it)
    async_cp16(w2p + it * 2048 + t * 8, &wl[it * 2048 + wb]);
  __syncthreads();
  // ---- MLP2 + residual ----
  #pragma unroll
  for (int d2t = 0; d2t < 8; ++d2t) {
    f32x4 acc = {0.f, 0.f, 0.f, 0.f};
    #pragma unroll
    for (int kk2 = 0; kk2 < 8; ++kk2) {
      U a; a.u = *(const uint4*)&wl[(d2t * 8 + kk2) * 512 + lo];
      acc = __builtin_amdgcn_mfma_f32_16x16x32_bf16(a.s, pf[kk2].s, acc, 0, 0, 0);
    }
    #pragma unroll
    for (int r = 0; r < 4; ++r) {
      const int d = d2t * 16 + g * 4 + r;
      out[((size_t)b * 128 + d) * 1024 + tw] = acc[r] + sh2[d] + vr[d2t][r];
    }
  }
}

}  // namespace

extern "C" void kernel_launch(void* const* d_in, const int* in_sizes, int n_in,
                              void* d_out, int out_size, void* d_ws, size_t ws_size,
                              hipStream_t stream) {
  const float* x  = (const float*)d_in[0];
  const float* Wq = (const float*)d_in[1];
  const float* gq = (const float*)d_in[2];
  const float* bq = (const float*)d_in[3];
  const float* mq = (const float*)d_in[4];
  const float* vq = (const float*)d_in[5];
  const float* Wp = (const float*)d_in[6];
  const float* gp = (const float*)d_in[7];
  const float* bp = (const float*)d_in[8];
  const float* mp = (const float*)d_in[9];
  const float* vp = (const float*)d_in[10];
  const float* W1 = (const float*)d_in[11];
  const float* g1 = (const float*)d_in[12];
  const float* b1 = (const float*)d_in[13];
  const float* m1 = (const float*)d_in[14];
  const float* v1 = (const float*)d_in[15];
  const float* W2 = (const float*)d_in[16];
  const float* g2 = (const float*)d_in[17];
  const float* b2 = (const float*)d_in[18];
  const float* m2 = (const float*)d_in[19];
  const float* v2 = (const float*)d_in[20];
  const float* ab = (const float*)d_in[21];
  float* out = (float*)d_out;

  char* ws = (char*)d_ws;
  uint16_t* qt   = (uint16_t*)(ws);                 // 8 MiB  [bh][32][1024]
  uint16_t* kwsp = (uint16_t*)(ws + (8ull << 20));  // 8 MiB  [bh][1024][32]
  uint16_t* vt   = (uint16_t*)(ws + (16ull << 20)); // 16 MiB sigma-permuted
  uint16_t* obuf = (uint16_t*)(ws + (32ull << 20)); // 16 MiB clip(o) bf16, fragment-native ob2
  uint16_t* wqkvb = (uint16_t*)(ws + (48ull << 20));
  uint16_t* wpb   = wqkvb + 65536;
  uint16_t* w1p   = wpb + 32768;
  uint16_t* w2p   = w1p + 32768;
  float* shq = (float*)(w2p + 32768);
  float* shp = shq + 512;
  float* sh1 = shp + 128;
  float* sh2 = sh1 + 256;

  k0_fold<<<644, 256, 0, stream>>>(Wq, gq, bq, mq, vq, Wp, gp, bp, mp, vp,
                                   W1, g1, b1, m1, v1, W2, g2, b2, m2, v2,
                                   wqkvb, shq, wpb, shp, w1p, sh1, w2p, sh2);
  k1_qkv<<<1024, 256, 0, stream>>>(x, wqkvb, shq, qt, kwsp, vt);
  k2_attn<<<1024, 256, 0, stream>>>(qt, kwsp, vt, ab, obuf);
  k345_mlp<<<512, 256, 0, stream>>>(obuf, x, wpb, shp, w1p, sh1, w2p, sh2, out);
  (void)in_sizes; (void)n_in; (void)out_size; (void)ws_size;
}